// Round 2
// baseline (12711.083 us; speedup 1.0000x reference)
//
#include <hip/hip_runtime.h>

// ---- problem constants (match reference) ----
constexpr int NY = 384, NX = 384, S = 4, NREC = 96, NT = 600;
constexpr int NN = NY * NX;
constexpr float D0 = 323.80102870228766f;  // 3*2500*ln(1000)/(2*20*4), f64->f32
constexpr float HALF_DT = 0.00025f;        // 0.5*DT
constexpr float DT2 = 2.5e-7f;             // DT*DT
constexpr float C0 = -1.0f / 12.0f, C1 = 4.0f / 3.0f, C2 = -2.5f;
constexpr float INV_DX2 = 0.0625f;         // 1/(DX*DX), exact

// ---- padded field geometry (2-cell zero guard ring -> no bounds checks) ----
constexpr int PX = NX + 4;                 // 388
constexpr int PY = NY + 4;                 // 388
constexpr int PNN = PX * PY;               // 150544

// ---- persistent-kernel geometry ----
constexpr int GBLK = 64;                   // blocks per shot group
constexpr int TPB  = 1024;                 // threads per block (16 waves)
constexpr int NBLK = S * GBLK;             // 256 blocks total (co-resident: 4096 waves)
constexpr int TPG  = GBLK * TPB;           // 65536 threads per group
constexpr int REM  = NN - 2 * TPG;         // 16384 threads own a 3rd cell

__device__ __forceinline__ float sigma_of(int y, int x) {
    float yf = (float)y, xf = (float)x;
    float l = fmaxf((20.0f - yf) / 20.0f, 0.0f);
    float r = fmaxf((yf - 363.0f) / 20.0f, 0.0f);
    float m = fmaxf(l, r);
    float sy = D0 * m * m;
    l = fmaxf((20.0f - xf) / 20.0f, 0.0f);
    r = fmaxf((xf - 363.0f) / 20.0f, 0.0f);
    m = fmaxf(l, r);
    float sx = D0 * m * m;
    return sy + sx;
}

// group barrier: accumulating-target, release-add / relaxed-spin / acquire-exit
__device__ __forceinline__ void group_barrier(unsigned int* bar, unsigned int& target) {
    __syncthreads();
    target += (unsigned)GBLK;
    if (threadIdx.x == 0) {
        __threadfence();  // drain this XCD L2 to coherent point
        __hip_atomic_fetch_add(bar, 1u, __ATOMIC_RELEASE, __HIP_MEMORY_SCOPE_AGENT);
        int guard = 0;
        while (__hip_atomic_load(bar, __ATOMIC_RELAXED, __HIP_MEMORY_SCOPE_AGENT) < target) {
            __builtin_amdgcn_s_sleep(1);
            if (++guard > 20000000) break;  // fail visibly, never hang
        }
        (void)__hip_atomic_load(bar, __ATOMIC_ACQUIRE, __HIP_MEMORY_SCOPE_AGENT);
    }
    __syncthreads();
}

// one cell update; returns u_next, outputs loaded u_cur (becomes next u_prev)
__device__ __forceinline__ float cell_step(const float* __restrict__ u, int po,
                                           float v2, float aa, float bb, float up,
                                           float& uc_out) {
    float uc  = u[po];
    float ym1 = u[po - PX];
    float ym2 = u[po - 2 * PX];
    float yp1 = u[po + PX];
    float yp2 = u[po + 2 * PX];
    float xm1 = u[po - 1];
    float xm2 = u[po - 2];
    float xp1 = u[po + 1];
    float xp2 = u[po + 2];
    float lyv = C0 * (ym2 + yp2) + C1 * (ym1 + yp1) + C2 * uc;
    float lxv = C0 * (xm2 + xp2) + C1 * (xm1 + xp1) + C2 * uc;
    float lap = (lyv + lxv) * INV_DX2;
    float num = 2.0f * uc - bb * up + v2 * lap;
    uc_out = uc;
    return num / aa;  // true f32 division, matches reference
}

__global__ __launch_bounds__(TPB) void prop_persistent(
    const float* __restrict__ vp,
    const float* __restrict__ src_amp,   // [S, NT]
    const int* __restrict__ src_loc,     // [S, 2]
    const int* __restrict__ rec_loc,     // [S*NREC, 2]
    float* __restrict__ out,             // [S*NREC, NT]
    float* __restrict__ ubuf,            // 2 * S * PNN floats, pre-zeroed
    unsigned int* __restrict__ bars)     // S * 64 uints, pre-zeroed
{
    const int blk  = blockIdx.x;
    const int s    = blk >> 6;          // shot group
    const int gb   = blk & 63;          // block within group
    const int tid  = threadIdx.x;
    const int gtid = gb * TPB + tid;    // 0..65535 within group

    unsigned int* bar = bars + s * 64;  // 256B-separated counters
    float* u0 = ubuf + (size_t)(2 * s) * PNN;
    float* u1 = u0 + PNN;

    // ---- per-thread cell setup (all 600 steps reuse these registers) ----
    const bool has3 = (gtid < REM);
    const int c0 = gtid, c1 = gtid + TPG, c2r = has3 ? (gtid + 2 * TPG) : gtid;

    int y0 = c0 / NX,  x0 = c0 - y0 * NX;
    int y1 = c1 / NX,  x1 = c1 - y1 * NX;
    int y2 = c2r / NX, x2 = c2r - y2 * NX;
    const int po0 = (y0 + 2) * PX + (x0 + 2);
    const int po1 = (y1 + 2) * PX + (x1 + 2);
    const int po2 = (y2 + 2) * PX + (x2 + 2);

    float v;
    v = vp[c0];  const float v2_0 = v * v * DT2;
    v = vp[c1];  const float v2_1 = v * v * DT2;
    v = vp[c2r]; const float v2_2 = v * v * DT2;
    float sg;
    sg = sigma_of(y0, x0); const float aa0 = 1.0f + HALF_DT * sg, bb0 = 1.0f - HALF_DT * sg;
    sg = sigma_of(y1, x1); const float aa1 = 1.0f + HALF_DT * sg, bb1 = 1.0f - HALF_DT * sg;
    sg = sigma_of(y2, x2); const float aa2 = 1.0f + HALF_DT * sg, bb2 = 1.0f - HALF_DT * sg;

    float up0 = 0.0f, up1 = 0.0f, up2 = 0.0f;  // u_prev lives in registers

    const int sy = src_loc[2 * s], sx = src_loc[2 * s + 1];
    const int src_po = (sy + 2) * PX + (sx + 2);
    const float* amp = src_amp + s * NT;

    const bool is_rec = (gb == 0) && (tid < NREC);
    int rec_po = 0, rec_off = 0;
    if (is_rec) {
        int r = s * NREC + tid;
        rec_po  = (rec_loc[2 * r] + 2) * PX + (rec_loc[2 * r + 1] + 2);
        rec_off = r * NT;
    }

    // fields are pre-zeroed by hipMemsetAsync (stream-ordered before this kernel)
    float* ucur = u0;
    float* unx  = u1;
    unsigned int target = 0;

    for (int t = 0; t < NT; ++t) {
        float uc;
        float un0 = cell_step(ucur, po0, v2_0, aa0, bb0, up0, uc); up0 = uc;
        float un1 = cell_step(ucur, po1, v2_1, aa1, bb1, up1, uc); up1 = uc;
        float un2 = 0.0f;
        if (has3) { un2 = cell_step(ucur, po2, v2_2, aa2, bb2, up2, uc); up2 = uc; }

        // source injection by owning thread
        if (po0 == src_po) un0 += amp[t] * v2_0;
        if (po1 == src_po) un1 += amp[t] * v2_1;
        if (has3 && po2 == src_po) un2 += amp[t] * v2_2;

        unx[po0] = un0;
        unx[po1] = un1;
        if (has3) unx[po2] = un2;

        group_barrier(bar, target);

        // record receivers for this step (overlaps next step's compute)
        if (is_rec) out[rec_off + t] = unx[rec_po];

        float* tmp = ucur; ucur = unx; unx = tmp;
    }
}

extern "C" void kernel_launch(void* const* d_in, const int* in_sizes, int n_in,
                              void* d_out, int out_size, void* d_ws, size_t ws_size,
                              hipStream_t stream)
{
    const float* vp      = (const float*)d_in[0];
    const float* src_amp = (const float*)d_in[1];
    const int*   src_loc = (const int*)d_in[2];
    const int*   rec_loc = (const int*)d_in[3];
    float* out = (float*)d_out;

    // ws layout: [bars: S*64 uints][ubuf: 2*S*PNN floats]
    unsigned int* bars = (unsigned int*)d_ws;
    float* ubuf = (float*)((char*)d_ws + S * 64 * sizeof(unsigned int));

    // zero barrier counters AND both padded wavefields (guard ring stays 0 forever)
    size_t zero_bytes = S * 64 * sizeof(unsigned int) + (size_t)(2 * S) * PNN * sizeof(float);
    hipMemsetAsync(d_ws, 0, zero_bytes, stream);

    prop_persistent<<<NBLK, TPB, 0, stream>>>(vp, src_amp, src_loc, rec_loc,
                                              out, ubuf, bars);
}

// Round 3
// 1175.210 us; speedup vs baseline: 10.8160x; 10.8160x over previous
//
#include <hip/hip_runtime.h>

// ---- problem constants ----
constexpr int NY = 384, NX = 384, S = 4, NREC = 96, NT = 600;
constexpr int K = 4;                    // timesteps per launch
constexpr int T = 48;                   // interior tile side
constexpr int L = 64;                   // extended tile side = T + 4K
constexpr int PAD = 8;                  // = 2K global guard
constexpr int PX = NX + 2 * PAD;        // 400
constexpr int PNN = PX * PX;            // 160000
constexpr int TB = NX / T;              // 8 tiles per dim
constexpr float D0 = 323.80102870228766f;
constexpr float HALF_DT = 0.00025f;     // 0.5*DT
constexpr float DT2 = 2.5e-7f;          // DT*DT
constexpr float C0 = -1.0f / 12.0f, C1 = 4.0f / 3.0f, C2 = -2.5f;
constexpr float INV_DX2 = 0.0625f;      // 1/DX^2 exact

__device__ __forceinline__ float sigma_of(int y, int x) {
    float yf = (float)y, xf = (float)x;
    float a = fmaxf((20.0f - yf) / 20.0f, 0.0f);
    float b = fmaxf((yf - 363.0f) / 20.0f, 0.0f);
    float m = fmaxf(a, b);
    float sy = D0 * m * m;
    a = fmaxf((20.0f - xf) / 20.0f, 0.0f);
    b = fmaxf((xf - 363.0f) / 20.0f, 0.0f);
    m = fmaxf(a, b);
    float sx = D0 * m * m;
    return sy + sx;
}

// padded coefficient fields; inva=0 outside the domain -> Dirichlet zero enforced
__global__ __launch_bounds__(256) void init_coeff(
    const float* __restrict__ vp,
    float* __restrict__ v2p, float* __restrict__ bpad, float* __restrict__ invap)
{
    int i = blockIdx.x * 256 + threadIdx.x;
    if (i >= PNN) return;
    int py = i / PX, px = i - py * PX;
    int dy = py - PAD, dx = px - PAD;
    bool in = ((unsigned)dy < (unsigned)NY) && ((unsigned)dx < (unsigned)NX);
    float v = in ? vp[dy * NX + dx] : 0.0f;
    float sig = sigma_of(dy, dx);
    float a = 1.0f + HALF_DT * sig;
    v2p[i]   = v * v * DT2;
    bpad[i]  = 1.0f - HALF_DT * sig;
    invap[i] = in ? (1.0f / a) : 0.0f;   // mask folded in
}

__device__ __forceinline__ float4 ld4g(const float* p) { return *(const float4*)p; }
__device__ __forceinline__ void st4g(float* p, float4 v) { *(float4*)p = v; }

// K=4 leapfrog steps, overlapped time-tiling in LDS.
__global__ __launch_bounds__(512) void stepK(
    float* __restrict__ ubuf,            // [S][4][PNN]: pin pair in, pout pair out
    const float* __restrict__ v2p, const float* __restrict__ bpad,
    const float* __restrict__ invap,
    const float* __restrict__ src_amp,   // [S, NT]
    const int* __restrict__ src_loc,     // [S, 2]
    const int* __restrict__ rec_loc,     // [S*NREC, 2]
    float* __restrict__ out,             // [S*NREC, NT]
    int t0, int pin, int pout)
{
    __shared__ __align__(16) float A0[L * L];
    __shared__ __align__(16) float A1[L * L];
    __shared__ int r_lidx[NREC];
    __shared__ int r_tout[NREC];
    __shared__ int r_cnt;

    const int tid = threadIdx.x;
    const int bx = blockIdx.x, by = blockIdx.y, s = blockIdx.z;

    const float* upIn = ubuf + (size_t)(s * 4 + pin) * PNN;
    const float* ucIn = upIn + PNN;
    float* upOut = ubuf + (size_t)(s * 4 + pout) * PNN;
    float* ucOut = upOut + PNN;

    const int py0 = by * T;           // padded-array row of local ly=0
    const int px0 = bx * T;
    const int gy0 = py0 - PAD;        // domain row of local ly=0
    const int gx0 = px0 - PAD;

    if (tid == 0) r_cnt = 0;

    // ---- source geometry (uniform per block) ----
    const int sy = src_loc[2 * s], sx = src_loc[2 * s + 1];
    const int sly = sy - gy0, slx = sx - gx0;
    const bool has_src = ((unsigned)sly < (unsigned)L) && ((unsigned)slx < (unsigned)L);
    const int sQuad = sly * 16 + (slx >> 2);
    const int sSub = slx & 3;
    const float4 amp4 = ld4g(&src_amp[s * NT + t0]);   // 16B-aligned: NT,t0 mult of 4

    // ---- per-thread setup: 2 quads (4 cells each) ----
    float4 up4[2], v24[2], bb4[2], ia4[2], sAdd[2], last[2];
#pragma unroll
    for (int it = 0; it < 2; ++it) {
        int q = tid + it * 512;
        int ly = q >> 4, qx = q & 15;
        int pa = (py0 + ly) * PX + px0 + qx * 4;
        up4[it] = ld4g(upIn + pa);
        float4 uc = ld4g(ucIn + pa);
        *(float4*)&A0[ly * 64 + qx * 4] = uc;
        v24[it] = ld4g(v2p + pa);
        bb4[it] = ld4g(bpad + pa);
        ia4[it] = ld4g(invap + pa);
        float4 sa = {0.f, 0.f, 0.f, 0.f};
        if (has_src && q == sQuad) {
            if (sSub == 0) sa.x = v24[it].x;
            else if (sSub == 1) sa.y = v24[it].y;
            else if (sSub == 2) sa.z = v24[it].z;
            else sa.w = v24[it].w;
        }
        sAdd[it] = sa;
        last[it] = make_float4(0.f, 0.f, 0.f, 0.f);
    }
    __syncthreads();   // covers r_cnt init + A0 writes

    // ---- receiver ownership scan (unique interior owner) ----
    if (tid < NREC) {
        int r = s * NREC + tid;
        int ry = rec_loc[2 * r], rx = rec_loc[2 * r + 1];
        if (ry >= by * T && ry < by * T + T && rx >= bx * T && rx < bx * T + T) {
            int k = atomicAdd(&r_cnt, 1);
            r_lidx[k] = (ry - gy0) * L + (rx - gx0);
            r_tout[k] = r * NT + t0;
        }
    }

    // ---- K sub-steps, valid region shrinks 2/side each ----
#pragma unroll
    for (int j = 0; j < K; ++j) {
        const int m = 2 * (j + 1);
        const float* Ain = (j & 1) ? A1 : A0;
        float* Aout = (j & 1) ? A0 : A1;
        const float aj = (j == 0) ? amp4.x : (j == 1) ? amp4.y : (j == 2) ? amp4.z : amp4.w;
        const bool srcOK = has_src && sly >= m && sly < L - m && slx >= m && slx < L - m;

#pragma unroll
        for (int it = 0; it < 2; ++it) {
            int q = tid + it * 512;
            int ly = q >> 4, qx = q & 15;
            if (ly >= m && ly < L - m && qx * 4 + 3 >= m && qx * 4 < L - m) {
                int lb = ly * 64 + qx * 4;
                float4 ym2 = *(const float4*)&Ain[lb - 128];
                float4 ym1 = *(const float4*)&Ain[lb - 64];
                float4 xc  = *(const float4*)&Ain[lb];
                float4 yp1 = *(const float4*)&Ain[lb + 64];
                float4 yp2 = *(const float4*)&Ain[lb + 128];
                float4 xm  = *(const float4*)&Ain[(qx > 0) ? lb - 4 : lb];   // clamp: feeds garbage-only cells
                float4 xp  = *(const float4*)&Ain[(qx < 15) ? lb + 4 : lb];

                float4 up = up4[it], v2 = v24[it], bb = bb4[it], ia = ia4[it];
                float4 res;
                {   // c=0: xm2=xm.z xm1=xm.w xp1=xc.y xp2=xc.z
                    float lyv = C0 * (ym2.x + yp2.x) + C1 * (ym1.x + yp1.x) + C2 * xc.x;
                    float lxv = C0 * (xm.z + xc.z) + C1 * (xm.w + xc.y) + C2 * xc.x;
                    float lap = (lyv + lxv) * INV_DX2;
                    res.x = (2.0f * xc.x - bb.x * up.x + v2.x * lap) * ia.x;
                }
                {   // c=1: xm.w, xc.x, xc.z, xc.w
                    float lyv = C0 * (ym2.y + yp2.y) + C1 * (ym1.y + yp1.y) + C2 * xc.y;
                    float lxv = C0 * (xm.w + xc.w) + C1 * (xc.x + xc.z) + C2 * xc.y;
                    float lap = (lyv + lxv) * INV_DX2;
                    res.y = (2.0f * xc.y - bb.y * up.y + v2.y * lap) * ia.y;
                }
                {   // c=2: xc.x, xc.y, xc.w, xp.x
                    float lyv = C0 * (ym2.z + yp2.z) + C1 * (ym1.z + yp1.z) + C2 * xc.z;
                    float lxv = C0 * (xc.x + xp.x) + C1 * (xc.y + xc.w) + C2 * xc.z;
                    float lap = (lyv + lxv) * INV_DX2;
                    res.z = (2.0f * xc.z - bb.z * up.z + v2.z * lap) * ia.z;
                }
                {   // c=3: xc.y, xc.z, xp.x, xp.y
                    float lyv = C0 * (ym2.w + yp2.w) + C1 * (ym1.w + yp1.w) + C2 * xc.w;
                    float lxv = C0 * (xc.y + xp.y) + C1 * (xc.z + xp.x) + C2 * xc.w;
                    float lap = (lyv + lxv) * INV_DX2;
                    res.w = (2.0f * xc.w - bb.w * up.w + v2.w * lap) * ia.w;
                }
                if (srcOK) {   // only the owner quad has nonzero sAdd
                    res.x += aj * sAdd[it].x;
                    res.y += aj * sAdd[it].y;
                    res.z += aj * sAdd[it].z;
                    res.w += aj * sAdd[it].w;
                }
                *(float4*)&Aout[lb] = res;
                up4[it] = xc;          // u_prev for next sub-step
                last[it] = res;        // final-field candidate
            }
        }
        __syncthreads();
        // record receivers for time t0+j from the just-written buffer
        if (tid < r_cnt) out[r_tout[tid] + j] = Aout[r_lidx[tid]];
    }

    // ---- write back interior of final pair: last=t0+K (cur), up4=t0+K-1 (prev) ----
#pragma unroll
    for (int it = 0; it < 2; ++it) {
        int q = tid + it * 512;
        int ly = q >> 4, qx = q & 15;
        if (ly >= PAD && ly < L - PAD && qx >= 2 && qx < 14) {
            int pa = (py0 + ly) * PX + px0 + qx * 4;
            st4g(ucOut + pa, last[it]);
            st4g(upOut + pa, up4[it]);
        }
    }
}

extern "C" void kernel_launch(void* const* d_in, const int* in_sizes, int n_in,
                              void* d_out, int out_size, void* d_ws, size_t ws_size,
                              hipStream_t stream)
{
    const float* vp      = (const float*)d_in[0];
    const float* src_amp = (const float*)d_in[1];
    const int*   src_loc = (const int*)d_in[2];
    const int*   rec_loc = (const int*)d_in[3];
    float* out = (float*)d_out;

    // ws layout: v2p | bpad | invap | ubuf[S][4][PNN]
    float* ws = (float*)d_ws;
    float* v2p   = ws;
    float* bpad  = v2p + PNN;
    float* invap = bpad + PNN;
    float* ubuf  = invap + PNN;

    // zero all wavefields every call (guard rings must be 0; ws is not re-poisoned)
    hipMemsetAsync(ubuf, 0, (size_t)S * 4 * PNN * sizeof(float), stream);
    init_coeff<<<(PNN + 255) / 256, 256, 0, stream>>>(vp, v2p, bpad, invap);

    for (int l = 0; l < NT / K; ++l) {
        int pin = (l & 1) ? 2 : 0;
        int pout = (l & 1) ? 0 : 2;
        stepK<<<dim3(TB, TB, S), 512, 0, stream>>>(
            ubuf, v2p, bpad, invap, src_amp, src_loc, rec_loc, out,
            l * K, pin, pout);
    }
}

// Round 4
// 897.288 us; speedup vs baseline: 14.1661x; 1.3097x over previous
//
#include <hip/hip_runtime.h>

// ---- problem constants ----
constexpr int NY = 384, NX = 384, S = 4, NREC = 96, NT = 600;
constexpr int K = 8;                    // timesteps per launch
constexpr int T = 48;                   // interior tile side
constexpr int L = 80;                   // extended tile side = T + 4K
constexpr int PAD = 16;                 // = 2K global guard
constexpr int PX = NX + 2 * PAD;        // 416
constexpr int PNN = PX * PX;            // 173056
constexpr int TB = NX / T;              // 8 tiles per dim
constexpr int SP = 84;                  // LDS row stride (floats), padded
constexpr float D0 = 323.80102870228766f;
constexpr float HALF_DT = 0.00025f;     // 0.5*DT
constexpr float DT2 = 2.5e-7f;          // DT*DT
constexpr float C0 = -1.0f / 12.0f, C1 = 4.0f / 3.0f, C2 = -2.5f;
constexpr float INV_DX2 = 0.0625f;      // 1/DX^2 exact

__device__ __forceinline__ float sigma_of(int y, int x) {
    float yf = (float)y, xf = (float)x;
    float a = fmaxf((20.0f - yf) / 20.0f, 0.0f);
    float b = fmaxf((yf - 363.0f) / 20.0f, 0.0f);
    float m = fmaxf(a, b);
    float sy = D0 * m * m;
    a = fmaxf((20.0f - xf) / 20.0f, 0.0f);
    b = fmaxf((xf - 363.0f) / 20.0f, 0.0f);
    m = fmaxf(a, b);
    float sx = D0 * m * m;
    return sy + sx;
}

__global__ __launch_bounds__(256) void init_coeff(
    const float* __restrict__ vp,
    float* __restrict__ v2p, float* __restrict__ bpad, float* __restrict__ invap)
{
    int i = blockIdx.x * 256 + threadIdx.x;
    if (i >= PNN) return;
    int py = i / PX, px = i - py * PX;
    int dy = py - PAD, dx = px - PAD;
    bool in = ((unsigned)dy < (unsigned)NY) && ((unsigned)dx < (unsigned)NX);
    float v = in ? vp[dy * NX + dx] : 0.0f;
    float sig = sigma_of(dy, dx);
    float a = 1.0f + HALF_DT * sig;
    v2p[i]   = v * v * DT2;
    bpad[i]  = 1.0f - HALF_DT * sig;
    invap[i] = in ? (1.0f / a) : 0.0f;   // Dirichlet mask folded in
}

__device__ __forceinline__ float4 ld4g(const float* p) { return *(const float4*)p; }
__device__ __forceinline__ void st4g(float* p, float4 v) { *(float4*)p = v; }
__device__ __forceinline__ float get4(const float4& v, int c) {
    return c == 0 ? v.x : c == 1 ? v.y : c == 2 ? v.z : v.w;
}
__device__ __forceinline__ void set4(float4& v, int c, float x) {
    if (c == 0) v.x = x; else if (c == 1) v.y = x; else if (c == 2) v.z = x; else v.w = x;
}

// 4-cell quad update. x-chain: [xm2a, xm1a, cen.x..w, xp1a, xp2a]
__device__ __forceinline__ float4 quad_update(
    float4 cen, float4 up, float4 v2, float4 bb, float4 ia,
    float4 ym2, float4 ym1, float4 yp1, float4 yp2,
    float xm2a, float xm1a, float xp1a, float xp2a)
{
    float4 r;
    float lyv, lxv, lap;
    lyv = C0 * (ym2.x + yp2.x) + C1 * (ym1.x + yp1.x) + C2 * cen.x;
    lxv = C0 * (xm2a + cen.z) + C1 * (xm1a + cen.y) + C2 * cen.x;
    lap = (lyv + lxv) * INV_DX2;
    r.x = (2.0f * cen.x - bb.x * up.x + v2.x * lap) * ia.x;
    lyv = C0 * (ym2.y + yp2.y) + C1 * (ym1.y + yp1.y) + C2 * cen.y;
    lxv = C0 * (xm1a + cen.w) + C1 * (cen.x + cen.z) + C2 * cen.y;
    lap = (lyv + lxv) * INV_DX2;
    r.y = (2.0f * cen.y - bb.y * up.y + v2.y * lap) * ia.y;
    lyv = C0 * (ym2.z + yp2.z) + C1 * (ym1.z + yp1.z) + C2 * cen.z;
    lxv = C0 * (cen.x + xp1a) + C1 * (cen.y + cen.w) + C2 * cen.z;
    lap = (lyv + lxv) * INV_DX2;
    r.z = (2.0f * cen.z - bb.z * up.z + v2.z * lap) * ia.z;
    lyv = C0 * (ym2.w + yp2.w) + C1 * (ym1.w + yp1.w) + C2 * cen.w;
    lxv = C0 * (cen.y + xp2a) + C1 * (cen.z + xp1a) + C2 * cen.w;
    lap = (lyv + lxv) * INV_DX2;
    r.w = (2.0f * cen.w - bb.w * up.w + v2.w * lap) * ia.w;
    return r;
}

// one sub-step for a vertical pair of quads (rows rl, rl+1 at cols qc4..qc4+3)
__device__ __forceinline__ void pair_step(
    const float* __restrict__ Ain, float* __restrict__ Aout,
    int m, int rl, int qc4, float aj,
    float4& cenL, float4& cenU, float4& upL, float4& upU,
    const float4& v2L, const float4& v2U, const float4& bbL, const float4& bbU,
    const float4& iaL, const float4& iaU, const float4& saL, const float4& saU)
{
    if (rl < m || rl >= L - m || qc4 + 3 < m || qc4 >= L - m) return;
    const int b = rl * SP + qc4;
    float4 rm2 = *(const float4*)&Ain[b - 2 * SP];   // row rl-2
    float4 rm1 = *(const float4*)&Ain[b - SP];       // row rl-1
    float4 rp2 = *(const float4*)&Ain[b + 2 * SP];   // row rl+2
    float4 rp3 = *(const float4*)&Ain[b + 3 * SP];   // row rl+3
    float2 xmL = *(const float2*)&Ain[b - 2];
    float2 xpL = *(const float2*)&Ain[b + 4];
    float2 xmU = *(const float2*)&Ain[b + SP - 2];
    float2 xpU = *(const float2*)&Ain[b + SP + 4];
    // lower: ym2=rm2 ym1=rm1 yp1=cenU yp2=rp2 ; upper: ym2=rm1 ym1=cenL yp1=rp2 yp2=rp3
    float4 rL = quad_update(cenL, upL, v2L, bbL, iaL, rm2, rm1, cenU, rp2,
                            xmL.x, xmL.y, xpL.x, xpL.y);
    float4 rU = quad_update(cenU, upU, v2U, bbU, iaU, rm1, cenL, rp2, rp3,
                            xmU.x, xmU.y, xpU.x, xpU.y);
    rL.x += aj * saL.x; rL.y += aj * saL.y; rL.z += aj * saL.z; rL.w += aj * saL.w;
    rU.x += aj * saU.x; rU.y += aj * saU.y; rU.z += aj * saU.z; rU.w += aj * saU.w;
    *(float4*)&Aout[b] = rL;
    *(float4*)&Aout[b + SP] = rU;
    upL = cenL; cenL = rL;
    upU = cenU; cenU = rU;
}

__device__ __forceinline__ void slot_setup(
    int p, int py0, int px0, int sly, int slx, bool has_src,
    const float* __restrict__ upIn, const float* __restrict__ ucIn,
    const float* __restrict__ v2p, const float* __restrict__ bpad,
    const float* __restrict__ invap, float* __restrict__ A0,
    int& rl, int& qc4,
    float4& cenL, float4& cenU, float4& upL, float4& upU,
    float4& v2L, float4& v2U, float4& bbL, float4& bbU,
    float4& iaL, float4& iaU, float4& saL, float4& saU)
{
    int pr = p / 20;
    qc4 = (p - pr * 20) * 4;
    rl = 2 * pr;
    int pa = (py0 + rl) * PX + px0 + qc4;
    upL = ld4g(upIn + pa);        upU = ld4g(upIn + pa + PX);
    cenL = ld4g(ucIn + pa);       cenU = ld4g(ucIn + pa + PX);
    *(float4*)&A0[rl * SP + qc4] = cenL;
    *(float4*)&A0[(rl + 1) * SP + qc4] = cenU;
    v2L = ld4g(v2p + pa);         v2U = ld4g(v2p + pa + PX);
    bbL = ld4g(bpad + pa);        bbU = ld4g(bpad + pa + PX);
    iaL = ld4g(invap + pa);       iaU = ld4g(invap + pa + PX);
    saL = make_float4(0.f, 0.f, 0.f, 0.f); saU = saL;
    if (has_src && slx >= qc4 && slx < qc4 + 4) {
        int c = slx - qc4;
        if (sly == rl)      set4(saL, c, get4(v2L, c));
        else if (sly == rl + 1) set4(saU, c, get4(v2U, c));
    }
}

__global__ __launch_bounds__(512) void stepK(
    float* __restrict__ ubuf,            // [S][4][PNN]
    const float* __restrict__ v2p, const float* __restrict__ bpad,
    const float* __restrict__ invap,
    const float* __restrict__ src_amp,   // [S, NT]
    const int* __restrict__ src_loc,     // [S, 2]
    const int* __restrict__ rec_loc,     // [S*NREC, 2]
    float* __restrict__ out,             // [S*NREC, NT]
    int t0, int pin, int pout)
{
    __shared__ __align__(16) float A0[SP * L];
    __shared__ __align__(16) float A1[SP * L];
    __shared__ int r_lidx[NREC];
    __shared__ int r_tout[NREC];
    __shared__ int r_cnt;

    const int tid = threadIdx.x;
    const int bx = blockIdx.x, by = blockIdx.y, s = blockIdx.z;

    const float* upIn = ubuf + (size_t)(s * 4 + pin) * PNN;
    const float* ucIn = upIn + PNN;
    float* upOut = ubuf + (size_t)(s * 4 + pout) * PNN;
    float* ucOut = upOut + PNN;

    const int py0 = by * T;            // padded row of local (0,0)
    const int px0 = bx * T;
    const int gy0 = py0 - PAD;         // domain coords of local (0,0)
    const int gx0 = px0 - PAD;

    if (tid == 0) r_cnt = 0;

    // source geometry
    const int sy = src_loc[2 * s], sx = src_loc[2 * s + 1];
    const int sly = sy - gy0, slx = sx - gx0;
    const bool has_src = ((unsigned)sly < (unsigned)L) && ((unsigned)slx < (unsigned)L);
    const float4 a0 = ld4g(&src_amp[s * NT + t0]);
    const float4 a1 = ld4g(&src_amp[s * NT + t0 + 4]);

    // ---- slot 0 (pairs 0..511) and slot 1 (pairs 512..799, tid<288) ----
    const bool act1 = (tid < 288);
    int rl0, qc40, rl1 = 2, qc41 = 0;
    float4 cenL0, cenU0, upL0, upU0, v2L0, v2U0, bbL0, bbU0, iaL0, iaU0, saL0, saU0;
    float4 cenL1 = {}, cenU1 = {}, upL1 = {}, upU1 = {}, v2L1 = {}, v2U1 = {},
           bbL1 = {}, bbU1 = {}, iaL1 = {}, iaU1 = {}, saL1 = {}, saU1 = {};

    slot_setup(tid, py0, px0, sly, slx, has_src, upIn, ucIn, v2p, bpad, invap, A0,
               rl0, qc40, cenL0, cenU0, upL0, upU0, v2L0, v2U0, bbL0, bbU0,
               iaL0, iaU0, saL0, saU0);
    if (act1)
        slot_setup(tid + 512, py0, px0, sly, slx, has_src, upIn, ucIn, v2p, bpad, invap, A0,
                   rl1, qc41, cenL1, cenU1, upL1, upU1, v2L1, v2U1, bbL1, bbU1,
                   iaL1, iaU1, saL1, saU1);
    __syncthreads();

    // receiver ownership scan (unique interior owner)
    if (tid < NREC) {
        int r = s * NREC + tid;
        int ry = rec_loc[2 * r], rx = rec_loc[2 * r + 1];
        if (ry >= by * T && ry < by * T + T && rx >= bx * T && rx < bx * T + T) {
            int k = atomicAdd(&r_cnt, 1);
            r_lidx[k] = (ry - gy0) * SP + (rx - gx0);
            r_tout[k] = r * NT + t0;
        }
    }

#pragma unroll
    for (int j = 0; j < K; ++j) {
        const int m = 2 * (j + 1);
        const float* Ain = (j & 1) ? A1 : A0;
        float* Aout = (j & 1) ? A0 : A1;
        const float aj = (j == 0) ? a0.x : (j == 1) ? a0.y : (j == 2) ? a0.z :
                         (j == 3) ? a0.w : (j == 4) ? a1.x : (j == 5) ? a1.y :
                         (j == 6) ? a1.z : a1.w;
        pair_step(Ain, Aout, m, rl0, qc40, aj, cenL0, cenU0, upL0, upU0,
                  v2L0, v2U0, bbL0, bbU0, iaL0, iaU0, saL0, saU0);
        if (act1)
            pair_step(Ain, Aout, m, rl1, qc41, aj, cenL1, cenU1, upL1, upU1,
                      v2L1, v2U1, bbL1, bbU1, iaL1, iaU1, saL1, saU1);
        __syncthreads();
        if (tid < r_cnt) out[r_tout[tid] + j] = Aout[r_lidx[tid]];
    }

    // ---- store interior of final pair: cen = u(t0+K), up = u(t0+K-1) ----
    if (rl0 >= PAD && rl0 < L - PAD && qc40 >= PAD && qc40 < L - PAD) {
        int pa = (py0 + rl0) * PX + px0 + qc40;
        st4g(ucOut + pa, cenL0);       st4g(upOut + pa, upL0);
        st4g(ucOut + pa + PX, cenU0);  st4g(upOut + pa + PX, upU0);
    }
    if (act1 && rl1 >= PAD && rl1 < L - PAD && qc41 >= PAD && qc41 < L - PAD) {
        int pa = (py0 + rl1) * PX + px0 + qc41;
        st4g(ucOut + pa, cenL1);       st4g(upOut + pa, upL1);
        st4g(ucOut + pa + PX, cenU1);  st4g(upOut + pa + PX, upU1);
    }
}

extern "C" void kernel_launch(void* const* d_in, const int* in_sizes, int n_in,
                              void* d_out, int out_size, void* d_ws, size_t ws_size,
                              hipStream_t stream)
{
    const float* vp      = (const float*)d_in[0];
    const float* src_amp = (const float*)d_in[1];
    const int*   src_loc = (const int*)d_in[2];
    const int*   rec_loc = (const int*)d_in[3];
    float* out = (float*)d_out;

    // ws layout: v2p | bpad | invap | ubuf[S][4][PNN]
    float* ws = (float*)d_ws;
    float* v2p   = ws;
    float* bpad  = v2p + PNN;
    float* invap = bpad + PNN;
    float* ubuf  = invap + PNN;

    hipMemsetAsync(ubuf, 0, (size_t)S * 4 * PNN * sizeof(float), stream);
    init_coeff<<<(PNN + 255) / 256, 256, 0, stream>>>(vp, v2p, bpad, invap);

    for (int l = 0; l < NT / K; ++l) {
        int pin = (l & 1) ? 2 : 0;
        int pout = (l & 1) ? 0 : 2;
        stepK<<<dim3(TB, TB, S), 512, 0, stream>>>(
            ubuf, v2p, bpad, invap, src_amp, src_loc, rec_loc, out,
            l * K, pin, pout);
    }
}